// Round 3
// baseline (24099.448 us; speedup 1.0000x reference)
//
#include <hip/hip_runtime.h>
#include <hip/hip_cooperative_groups.h>

namespace cg = cooperative_groups;

#define VOCAB   32000
#define DIM     512
#define HDIM    512
#define BATCH   32
#define TSTEPS  128
#define TOPKN   5
#define CAND    8
#define BOSTOK  1
#define ALPHA   0.2f
#define G3H     1536

#define NBLK    256
#define NTHR    256
#define GEMMBLK 250
#define CPB     128

// ---------------- shared small helpers ----------------
__device__ __forceinline__ bool better(float v1, int i1, float v2, int i2) {
    // jax.lax.top_k order: value desc, index asc on ties
    return (v1 > v2) || (v1 == v2 && i1 < i2);
}

__device__ __forceinline__ void ins5(float (&lv)[TOPKN], int (&li)[TOPKN], float v, int i) {
    if (better(v, i, lv[4], li[4])) {
        lv[4] = v; li[4] = i;
#pragma unroll
        for (int q = 4; q > 0; --q) {
            if (better(lv[q], li[q], lv[q - 1], li[q - 1])) {
                float tv = lv[q]; lv[q] = lv[q - 1]; lv[q - 1] = tv;
                int   ti = li[q]; li[q] = li[q - 1]; li[q - 1] = ti;
            }
        }
    }
}

__device__ __forceinline__ unsigned f2bf(float f) {   // f32 -> bf16 RNE
    unsigned u = __float_as_uint(f);
    return (u + 0x7FFFu + ((u >> 16) & 1u)) >> 16;
}

// =====================================================================
// ===================== NEW MFMA + rescore path =======================
// =====================================================================

typedef __bf16 bf16x8 __attribute__((ext_vector_type(8)));
typedef float  f32x4  __attribute__((ext_vector_type(4)));

struct SMemN_run {
    unsigned afrag[2][16][64][4];   // A fragments (bf16 pairs) 32768 B
    float pwv[4][BATCH][TOPKN];     // per-wave topk partials
    int   pwi[4][BATCH][TOPKN];
    float xgs[BATCH][6];            // phase C xg staging
    int   sel[BATCH];
    float mrgv[4]; int mrgi[4]; int mrgt[4];
};
struct SMemN_pro { float tile[64][129]; };
union  SMemN { SMemN_pro pro; SMemN_run run; };

// hg = h2 @ U + b_r, block j's 192-entry slice (reads full h2, U_T rows)
__device__ __forceinline__ void hg_compute(int j, int tid, const float* __restrict__ h2,
                                           const float* __restrict__ UT,
                                           const float* __restrict__ b_r,
                                           float* __restrict__ hg) {
    if (tid < 192) {
        const int g  = j * 192 + tid;
        const int bb = g / G3H;
        const int c  = g - bb * G3H;
        const float4* hp = (const float4*)(h2 + bb * HDIM);
        const float4* up = (const float4*)(UT + (size_t)c * HDIM);
        float a = b_r[c];
#pragma unroll 4
        for (int i = 0; i < HDIM / 4; ++i) {
            float4 h = hp[i], u = up[i];
            a = fmaf(h.x, u.x, fmaf(h.y, u.y, fmaf(h.z, u.z, fmaf(h.w, u.w, a))));
        }
        hg[g] = a;
    }
}

__device__ void prologue_new(SMemN& s, int j, int tid,
    const float* __restrict__ Wo, const float* __restrict__ U,
    const float* __restrict__ Wx, const float* __restrict__ ctx,
    unsigned* __restrict__ WoPk, float* __restrict__ WoT,
    float* __restrict__ UT, float* __restrict__ WxT, float* __restrict__ h2)
{
    if (tid < 64) {     // h2 init: block j owns h-cols {2j, 2j+1}
        const int bb = tid >> 1, c = 2 * j + (tid & 1);
        h2[bb * HDIM + c] = ctx[bb * HDIM + c];
    }
    for (int i = tid; i < 6 * DIM; i += NTHR) {   // U_T / Wx_T rows (6 gate-cols)
        const int rr = i >> 9, k = i & 511;
        const int gc = (rr >> 1) * HDIM + 2 * j + (rr & 1);
        UT[(size_t)gc * DIM + k]  = U[(size_t)k * G3H + gc];
        WxT[(size_t)gc * DIM + k] = Wx[(size_t)k * G3H + gc];
    }
    if (j < GEMMBLK) {
        for (int chunk = 0; chunk < 8; ++chunk) {
            const int k0 = chunk * 64;
            __syncthreads();
#pragma unroll
            for (int it = 0; it < 8; ++it) {      // coalesced f32 tile load [64][128]
                const int idx = tid + it * NTHR;
                const int kk = idx >> 5, c4 = (idx & 31) << 2;
                const float4 v = *(const float4*)(Wo + (size_t)(k0 + kk) * VOCAB + j * CPB + c4);
                s.pro.tile[kk][c4] = v.x; s.pro.tile[kk][c4 + 1] = v.y;
                s.pro.tile[kk][c4 + 2] = v.z; s.pro.tile[kk][c4 + 3] = v.w;
            }
            __syncthreads();
            {   // Wo_T f32 (contiguous k rows)
                const int kh = tid >> 7, c = tid & 127;
                float* dst = WoT + ((size_t)j * CPB + c) * DIM + k0 + kh * 32;
#pragma unroll
                for (int kk = 0; kk < 32; ++kk) dst[kk] = s.pro.tile[kh * 32 + kk][c];
            }
            // Wo packed bf16 in MFMA B-frag order
#pragma unroll
            for (int uu = 0; uu < 4; ++uu) {
                const int u = tid + uu * NTHR;
                const int kss = u >> 9, nt = (u >> 6) & 7, ll = u & 63;
                const int kb = kss * 32 + ((ll >> 4) << 3);
                const int c  = nt * 16 + (ll & 15);
                unsigned d[4];
#pragma unroll
                for (int e2 = 0; e2 < 4; ++e2) {
                    const unsigned lo = f2bf(s.pro.tile[kb + 2 * e2][c]);
                    const unsigned hi = f2bf(s.pro.tile[kb + 2 * e2 + 1][c]);
                    d[e2] = lo | (hi << 16);
                }
                const int ksg = chunk * 2 + kss;
                uint4* dst = (uint4*)WoPk + ((((size_t)j * 16 + ksg) * 8 + nt) * 64 + ll);
                *dst = *(const uint4*)d;
            }
        }
    }
}

__device__ __forceinline__ void phaseA_new(SMemN& s, int j, int tid, int t,
    const unsigned* __restrict__ WoPk, const float* __restrict__ bo,
    const float* __restrict__ h2, const float* __restrict__ UT,
    const float* __restrict__ b_r, float* __restrict__ out,
    float* __restrict__ hg, float* __restrict__ pval, int* __restrict__ pidx)
{
    // ---- stage A-frags (h2 -> bf16, MFMA A layout) ----
#pragma unroll
    for (int q = 0; q < 8; ++q) {
        const int f = tid + q * NTHR;                // 0..2047
        const int m = f >> 10, ks = (f >> 6) & 15, lf = f & 63;
        const int row = (lf & 15) + 16 * m;
        const int kb  = ks * 32 + ((lf >> 4) << 3);
        const float4* hp = (const float4*)(h2 + row * DIM + kb);
        const float4 a0 = hp[0], a1 = hp[1];
        unsigned* d = &s.run.afrag[m][ks][lf][0];
        d[0] = f2bf(a0.x) | (f2bf(a0.y) << 16);
        d[1] = f2bf(a0.z) | (f2bf(a0.w) << 16);
        d[2] = f2bf(a1.x) | (f2bf(a1.y) << 16);
        d[3] = f2bf(a1.z) | (f2bf(a1.w) << 16);
    }
    __syncthreads();
    const int w = tid >> 6, l = tid & 63;
    if (j < GEMMBLK) {
        f32x4 acc[2][2];
        acc[0][0] = {0.f, 0.f, 0.f, 0.f}; acc[0][1] = {0.f, 0.f, 0.f, 0.f};
        acc[1][0] = {0.f, 0.f, 0.f, 0.f}; acc[1][1] = {0.f, 0.f, 0.f, 0.f};
        const uint4* wpk = (const uint4*)WoPk;
#pragma unroll 4
        for (int ks = 0; ks < 16; ++ks) {
            const uint4 b0 = wpk[(((size_t)j * 16 + ks) * 8 + 2 * w) * 64 + l];
            const uint4 b1 = wpk[(((size_t)j * 16 + ks) * 8 + 2 * w + 1) * 64 + l];
            const uint4 a0 = *(const uint4*)&s.run.afrag[0][ks][l][0];
            const uint4 a1 = *(const uint4*)&s.run.afrag[1][ks][l][0];
            const bf16x8 A0 = __builtin_bit_cast(bf16x8, a0);
            const bf16x8 A1 = __builtin_bit_cast(bf16x8, a1);
            const bf16x8 B0 = __builtin_bit_cast(bf16x8, b0);
            const bf16x8 B1 = __builtin_bit_cast(bf16x8, b1);
            acc[0][0] = __builtin_amdgcn_mfma_f32_16x16x32_bf16(A0, B0, acc[0][0], 0, 0, 0);
            acc[0][1] = __builtin_amdgcn_mfma_f32_16x16x32_bf16(A0, B1, acc[0][1], 0, 0, 0);
            acc[1][0] = __builtin_amdgcn_mfma_f32_16x16x32_bf16(A1, B0, acc[1][0], 0, 0, 0);
            acc[1][1] = __builtin_amdgcn_mfma_f32_16x16x32_bf16(A1, B1, acc[1][1], 0, 0, 0);
        }
        const int c0 = j * CPB + (2 * w) * 16 + (l & 15);
        const int c1 = j * CPB + (2 * w + 1) * 16 + (l & 15);
        const float bo0 = bo[c0], bo1 = bo[c1];
#pragma unroll
        for (int m = 0; m < 2; ++m) {
#pragma unroll
            for (int r = 0; r < 4; ++r) {
                const int b = 16 * m + ((l >> 4) << 2) + r;
                const float v0 = acc[m][0][r] + bo0;
                const float v1 = acc[m][1][r] + bo1;
                __builtin_nontemporal_store(v0, out + ((size_t)b * TSTEPS + t) * VOCAB + c0);
                __builtin_nontemporal_store(v1, out + ((size_t)b * TSTEPS + t) * VOCAB + c1);
                float lv[TOPKN]; int li[TOPKN];
#pragma unroll
                for (int q = 0; q < TOPKN; ++q) { lv[q] = -INFINITY; li[q] = 0x7fffffff; }
                ins5(lv, li, v0, c0);
                ins5(lv, li, v1, c1);
#pragma unroll
                for (int mask = 1; mask < 16; mask <<= 1) {
                    float ov[TOPKN]; int oi[TOPKN];
#pragma unroll
                    for (int q = 0; q < TOPKN; ++q) {
                        ov[q] = __shfl_xor(lv[q], mask);
                        oi[q] = __shfl_xor(li[q], mask);
                    }
#pragma unroll
                    for (int q = 0; q < TOPKN; ++q) ins5(lv, li, ov[q], oi[q]);
                }
                if ((l & 15) == 0) {
#pragma unroll
                    for (int q = 0; q < TOPKN; ++q) { s.run.pwv[w][b][q] = lv[q]; s.run.pwi[w][b][q] = li[q]; }
                }
            }
        }
    }
    hg_compute(j, tid, h2, UT, b_r, hg);   // hg for step t+1
    __syncthreads();
    if (j < GEMMBLK && tid < BATCH) {
        float lv[TOPKN]; int li[TOPKN];
#pragma unroll
        for (int q = 0; q < TOPKN; ++q) { lv[q] = -INFINITY; li[q] = 0x7fffffff; }
#pragma unroll
        for (int w4 = 0; w4 < 4; ++w4)
#pragma unroll
            for (int q = 0; q < TOPKN; ++q) ins5(lv, li, s.run.pwv[w4][tid][q], s.run.pwi[w4][tid][q]);
        const size_t base = ((size_t)tid * NBLK + j) * TOPKN;
#pragma unroll
        for (int q = 0; q < TOPKN; ++q) { pval[base + q] = lv[q]; pidx[base + q] = li[q]; }
    }
}

__device__ __forceinline__ void phaseB_new(SMemN& s, int j, int tid,
    const float* __restrict__ pval, const int* __restrict__ pidx,
    const float* __restrict__ h2, const float* __restrict__ WoT,
    const float* __restrict__ bo, float* __restrict__ exV, int* __restrict__ exI)
{
    const int bat = j >> 3;
    float lv[TOPKN]; int li[TOPKN];
    if (tid < GEMMBLK) {
        const size_t base = ((size_t)bat * NBLK + tid) * TOPKN;
#pragma unroll
        for (int q = 0; q < TOPKN; ++q) { lv[q] = pval[base + q]; li[q] = pidx[base + q]; }
    } else {
#pragma unroll
        for (int q = 0; q < TOPKN; ++q) { lv[q] = -INFINITY; li[q] = 0x7fffffff; }
    }
    int cnd = 0;
    const int myrank = j & 7;
    for (int r = 0; r < CAND; ++r) {
        float cv = lv[0]; int ci = li[0]; int ct = tid;
#pragma unroll
        for (int mask = 1; mask < 64; mask <<= 1) {
            const float ov = __shfl_xor(cv, mask);
            const int   oi = __shfl_xor(ci, mask);
            const int   ot = __shfl_xor(ct, mask);
            if (better(ov, oi, cv, ci)) { cv = ov; ci = oi; ct = ot; }
        }
        if ((tid & 63) == 0) { s.run.mrgv[tid >> 6] = cv; s.run.mrgi[tid >> 6] = ci; s.run.mrgt[tid >> 6] = ct; }
        __syncthreads();
        float bv = s.run.mrgv[0]; int bi_ = s.run.mrgi[0]; int bt = s.run.mrgt[0];
#pragma unroll
        for (int wq = 1; wq < 4; ++wq)
            if (better(s.run.mrgv[wq], s.run.mrgi[wq], bv, bi_)) { bv = s.run.mrgv[wq]; bi_ = s.run.mrgi[wq]; bt = s.run.mrgt[wq]; }
        if (r == myrank) cnd = bi_;
        __syncthreads();
        if (tid == bt) {
            lv[0] = lv[1]; li[0] = li[1]; lv[1] = lv[2]; li[1] = li[2];
            lv[2] = lv[3]; li[2] = li[3]; lv[3] = lv[4]; li[3] = li[4];
            lv[4] = -INFINITY; li[4] = 0x7fffffff;
        }
    }
    // exact f32 rescore of candidate (bat, myrank)
    if (tid < 64) {
        const float4* wp = (const float4*)(WoT + (size_t)cnd * DIM);
        const float4* hp = (const float4*)(h2 + bat * HDIM);
        float a = 0.f;
#pragma unroll
        for (int ii = 0; ii < 2; ++ii) {
            const int i = tid + ii * 64;
            const float4 wv = wp[i], hv = hp[i];
            a = fmaf(hv.x, wv.x, fmaf(hv.y, wv.y, fmaf(hv.z, wv.z, fmaf(hv.w, wv.w, a))));
        }
#pragma unroll
        for (int mask = 1; mask < 64; mask <<= 1) a += __shfl_xor(a, mask);
        if (tid == 0) { exV[bat * CAND + myrank] = a + bo[cnd]; exI[bat * CAND + myrank] = cnd; }
    }
}

__device__ __forceinline__ void phaseC_new(SMemN& s, int j, int tid, int t,
    const float* __restrict__ E, const float* __restrict__ WxT,
    const float* __restrict__ b_i, const int* __restrict__ rix,
    const float* __restrict__ hg, const float* __restrict__ exV,
    const int* __restrict__ exI, float* __restrict__ h2)
{
    if (tid < BATCH) {
        int sl = BOSTOK;
        if (t > 0) {
            float lv[TOPKN]; int li[TOPKN];
#pragma unroll
            for (int q = 0; q < TOPKN; ++q) { lv[q] = -INFINITY; li[q] = 0x7fffffff; }
#pragma unroll
            for (int r = 0; r < CAND; ++r) ins5(lv, li, exV[tid * CAND + r], exI[tid * CAND + r]);
            sl = li[rix[(t - 1) * BATCH + tid]];
        }
        s.run.sel[tid] = sl;
    }
    __syncthreads();
    if (tid < 192) {
        const int bb = tid & 31, p = tid >> 5;                    // 32 batches x 6 gate-cols
        const int gc = (p >> 1) * HDIM + 2 * j + (p & 1);
        const float4* er = (const float4*)(E + (size_t)s.run.sel[bb] * DIM);
        const float4* wx = (const float4*)(WxT + (size_t)gc * DIM);
        float a = b_i[gc];
#pragma unroll 2
        for (int i = 0; i < DIM / 4; ++i) {
            const float4 e4 = er[i], w4 = wx[i];
            const float x0 = e4.x > 0.f ? e4.x : ALPHA * e4.x;
            const float x1 = e4.y > 0.f ? e4.y : ALPHA * e4.y;
            const float x2 = e4.z > 0.f ? e4.z : ALPHA * e4.z;
            const float x3 = e4.w > 0.f ? e4.w : ALPHA * e4.w;
            a = fmaf(x0, w4.x, fmaf(x1, w4.y, fmaf(x2, w4.z, fmaf(x3, w4.w, a))));
        }
        s.run.xgs[bb][p] = a;
    }
    __syncthreads();
    if (tid < 64) {
        const int bb = tid >> 1, q = tid & 1;
        const int hc = 2 * j + q;
        const float xz = s.run.xgs[bb][q], xr = s.run.xgs[bb][2 + q], xh = s.run.xgs[bb][4 + q];
        const float* hgb = hg + (size_t)bb * G3H;
        const float hz = hgb[hc], hr = hgb[HDIM + hc], hh = hgb[2 * HDIM + hc];
        const float z   = 1.f / (1.f + expf(-(xz + hz)));
        const float r   = 1.f / (1.f + expf(-(xr + hr)));
        const float cd  = tanhf(xh + r * hh);
        const float hold = h2[bb * HDIM + hc];
        h2[bb * HDIM + hc] = z * hold + (1.f - z) * cd;
    }
}

static __global__ void __launch_bounds__(NTHR, 1)
gru_mfma(const float* __restrict__ E,  const float* __restrict__ Wx,
         const float* __restrict__ U,  const float* __restrict__ b_i,
         const float* __restrict__ b_r, const float* __restrict__ Wo,
         const float* __restrict__ bo, const float* __restrict__ ctx,
         const int* __restrict__ rix,  float* __restrict__ out,
         unsigned* __restrict__ WoPk,  float* __restrict__ WoT,
         float* __restrict__ UT,       float* __restrict__ WxT,
         float* __restrict__ h2,       float* __restrict__ hg,
         float* __restrict__ pval,     int* __restrict__ pidx,
         float* __restrict__ exV,      int* __restrict__ exI)
{
    cg::grid_group grid = cg::this_grid();
    const int j = blockIdx.x, tid = threadIdx.x;
    __shared__ SMemN s;
    prologue_new(s, j, tid, Wo, U, Wx, ctx, WoPk, WoT, UT, WxT, h2);
    grid.sync();
    hg_compute(j, tid, h2, UT, b_r, hg);   // hg_0 = ctx @ U + b_r
    grid.sync();
    for (int t = 0; t < TSTEPS; ++t) {
        if (t > 0) phaseB_new(s, j, tid, pval, pidx, h2, WoT, bo, exV, exI);
        grid.sync();
        phaseC_new(s, j, tid, t, E, WxT, b_i, rix, hg, exV, exI, h2);
        grid.sync();
        phaseA_new(s, j, tid, t, WoPk, bo, h2, UT, b_r, out, hg, pval, pidx);
        grid.sync();
    }
}

// =====================================================================
// ================= round-2 f32 fallback (proven) =====================
// =====================================================================

#define KH      256
#define H2LD    (KH + 1)

struct alignas(16) SMem {
    float h2h[BATCH][H2LD];
    float sx[DIM];
    float dd[3][64];
    float mbv[4][BATCH][TOPKN];
    int   mbi[4][BATCH][TOPKN];
    float mrgv[4];
    int   mrgi[4];
    int   mrgt[4];
};

__device__ __forceinline__ float dot256(const float* __restrict__ M, const float* sv,
                                        int c, int kb, float acc) {
    const float* p = M + (size_t)kb * G3H + c;
    float wa[32], wb[32];
#pragma unroll
    for (int u = 0; u < 32; ++u) wa[u] = p[(size_t)u * G3H];
    for (int k0 = 0; k0 < KH; k0 += 64) {
#pragma unroll
        for (int u = 0; u < 32; ++u) wb[u] = p[(size_t)(k0 + 32 + u) * G3H];
#pragma unroll
        for (int u = 0; u < 32; ++u) acc = fmaf(sv[k0 + u], wa[u], acc);
        if (k0 + 64 < KH) {
#pragma unroll
            for (int u = 0; u < 32; ++u) wa[u] = p[(size_t)(k0 + 64 + u) * G3H];
        }
#pragma unroll
        for (int u = 0; u < 32; ++u) acc = fmaf(sv[k0 + 32 + u], wb[u], acc);
    }
    return acc;
}

__device__ __forceinline__ void stage_half(SMem& s, const float* __restrict__ src,
                                           int kb, int tid) {
#pragma unroll
    for (int it = 0; it < 8; ++it) {
        const int i  = tid + it * NTHR;
        const int bb = i >> 6;
        const int k4 = i & 63;
        const float4 v = *(const float4*)(src + (size_t)bb * DIM + kb + k4 * 4);
        float* d = &s.h2h[bb][k4 * 4];
        d[0] = v.x; d[1] = v.y; d[2] = v.z; d[3] = v.w;
    }
}

__device__ __forceinline__ void loadg(float4 (&wv)[8], float (&av)[8][4],
                                      const float* __restrict__ wp, const SMem& s,
                                      int bg, int kb, int k0) {
#pragma unroll
    for (int u = 0; u < 8; ++u) {
        wv[u] = *(const float4*)(wp + (size_t)(kb + k0 + u) * VOCAB);
#pragma unroll
        for (int bi = 0; bi < 4; ++bi) av[u][bi] = s.h2h[bg * 4 + bi][k0 + u];
    }
}

__device__ __forceinline__ void fmacg(float (&acc)[4][4], const float4 (&wv)[8],
                                      const float (&av)[8][4]) {
#pragma unroll
    for (int u = 0; u < 8; ++u) {
#pragma unroll
        for (int bi = 0; bi < 4; ++bi) {
            const float a = av[u][bi];
            acc[bi][0] = fmaf(a, wv[u].x, acc[bi][0]);
            acc[bi][1] = fmaf(a, wv[u].y, acc[bi][1]);
            acc[bi][2] = fmaf(a, wv[u].z, acc[bi][2]);
            acc[bi][3] = fmaf(a, wv[u].w, acc[bi][3]);
        }
    }
}

__device__ __forceinline__ void prologue_hg(SMem& s, int j, int tid,
                                            const float* __restrict__ U,
                                            const float* __restrict__ b_r,
                                            const float* __restrict__ hsrc,
                                            float* __restrict__ hg) {
    const int g  = j * 192 + tid;
    const int bb = (tid < 192) ? (g / G3H) : 0;
    const int c  = (tid < 192) ? (g - bb * G3H) : 0;
    float hacc = (tid < 192) ? b_r[c] : 0.f;
    for (int half = 0; half < 2; ++half) {
        const int kb = half * KH;
        __syncthreads();
        stage_half(s, hsrc, kb, tid);
        __syncthreads();
        if (tid < 192) hacc = dot256(U, s.h2h[bb], c, kb, hacc);
    }
    if (tid < 192) hg[g] = hacc;
}

__device__ __forceinline__ void phaseA(SMem& s, int j, int tid, int t,
    const float* __restrict__ U,  const float* __restrict__ b_r,
    const float* __restrict__ Wo, const float* __restrict__ bo,
    const float* __restrict__ hsrc, float* __restrict__ out,
    float* __restrict__ hg, float* __restrict__ pval, int* __restrict__ pidx)
{
    const int w   = tid >> 6;
    const int l   = tid & 63;
    const int bg  = l >> 3;
    const int cg2 = l & 7;
    const int cbase = j * CPB + w * 32 + cg2 * 4;
    const bool gemmer = (j < GEMMBLK);

    const int g     = j * 192 + tid;
    const int hb_bb = (tid < 192) ? (g / G3H) : 0;
    const int hb_c  = (tid < 192) ? (g - hb_bb * G3H) : 0;
    float hacc = (tid < 192) ? b_r[hb_c] : 0.f;

    float acc[4][4] = {};

    for (int half = 0; half < 2; ++half) {
        const int kb = half * KH;
        __syncthreads();
        stage_half(s, hsrc, kb, tid);
        __syncthreads();
        if (gemmer) {
            const float* wp = Wo + cbase;
            float4 wva[8], wvb[8];
            float  ava[8][4], avb[8][4];
            loadg(wva, ava, wp, s, bg, kb, 0);
            for (int k0 = 0; k0 < KH; k0 += 16) {
                loadg(wvb, avb, wp, s, bg, kb, k0 + 8);
                fmacg(acc, wva, ava);
                if (k0 + 16 < KH) loadg(wva, ava, wp, s, bg, kb, k0 + 16);
                fmacg(acc, wvb, avb);
            }
        }
        if (tid < 192) hacc = dot256(U, s.h2h[hb_bb], hb_c, kb, hacc);
    }

    if (tid < 192) hg[g] = hacc;

    if (gemmer) {
        const float4 bov = *(const float4*)(bo + cbase);
#pragma unroll
        for (int bi = 0; bi < 4; ++bi) {
            const int bb = bg * 4 + bi;
            float4 v;
            v.x = acc[bi][0] + bov.x;
            v.y = acc[bi][1] + bov.y;
            v.z = acc[bi][2] + bov.z;
            v.w = acc[bi][3] + bov.w;
            *(float4*)(out + ((size_t)bb * TSTEPS + t) * VOCAB + cbase) = v;

            float lv[TOPKN]; int li[TOPKN];
#pragma unroll
            for (int q = 0; q < TOPKN; ++q) { lv[q] = -INFINITY; li[q] = 0x7fffffff; }
            ins5(lv, li, v.x, cbase + 0);
            ins5(lv, li, v.y, cbase + 1);
            ins5(lv, li, v.z, cbase + 2);
            ins5(lv, li, v.w, cbase + 3);
#pragma unroll
            for (int mask = 1; mask < 8; mask <<= 1) {
                float ov[TOPKN]; int oi[TOPKN];
#pragma unroll
                for (int q = 0; q < TOPKN; ++q) {
                    ov[q] = __shfl_xor(lv[q], mask);
                    oi[q] = __shfl_xor(li[q], mask);
                }
#pragma unroll
                for (int q = 0; q < TOPKN; ++q) ins5(lv, li, ov[q], oi[q]);
            }
            if (cg2 == 0) {
#pragma unroll
                for (int q = 0; q < TOPKN; ++q) { s.mbv[w][bb][q] = lv[q]; s.mbi[w][bb][q] = li[q]; }
            }
        }
    }
    __syncthreads();
    if (gemmer && tid < BATCH) {
        float lv[TOPKN]; int li[TOPKN];
#pragma unroll
        for (int q = 0; q < TOPKN; ++q) { lv[q] = -INFINITY; li[q] = 0x7fffffff; }
#pragma unroll
        for (int w4 = 0; w4 < 4; ++w4)
#pragma unroll
            for (int q = 0; q < TOPKN; ++q) ins5(lv, li, s.mbv[w4][tid][q], s.mbi[w4][tid][q]);
        const size_t base = ((size_t)tid * NBLK + j) * TOPKN;
#pragma unroll
        for (int q = 0; q < TOPKN; ++q) { pval[base + q] = lv[q]; pidx[base + q] = li[q]; }
    }
}

__device__ __forceinline__ void phaseB(SMem& s, int j, int tid, int t,
    const float* __restrict__ E,   const float* __restrict__ Wx,
    const float* __restrict__ b_i, const int* __restrict__ rix,
    const float* __restrict__ hg,  const float* __restrict__ pval,
    const int* __restrict__ pidx,  const float* __restrict__ hcur,
    float* __restrict__ hnxt)
{
    const int bat = j >> 3;
    const int jj  = (j & 7) * 64;
    int sel = BOSTOK;
    if (t > 0) {
        float lv[TOPKN]; int li[TOPKN];
        if (tid < GEMMBLK) {
            const size_t base = ((size_t)bat * NBLK + tid) * TOPKN;
#pragma unroll
            for (int q = 0; q < TOPKN; ++q) { lv[q] = pval[base + q]; li[q] = pidx[base + q]; }
        } else {
#pragma unroll
            for (int q = 0; q < TOPKN; ++q) { lv[q] = -INFINITY; li[q] = 0x7fffffff; }
        }
        const int ridx = rix[(t - 1) * BATCH + bat];
        for (int r = 0; r < TOPKN; ++r) {
            float cv = lv[0]; int ci = li[0]; int ct = tid;
#pragma unroll
            for (int mask = 1; mask < 64; mask <<= 1) {
                const float ov = __shfl_xor(cv, mask);
                const int   oi = __shfl_xor(ci, mask);
                const int   ot = __shfl_xor(ct, mask);
                if (better(ov, oi, cv, ci)) { cv = ov; ci = oi; ct = ot; }
            }
            if ((tid & 63) == 0) { s.mrgv[tid >> 6] = cv; s.mrgi[tid >> 6] = ci; s.mrgt[tid >> 6] = ct; }
            __syncthreads();
            float bv = s.mrgv[0]; int bi_ = s.mrgi[0]; int bt = s.mrgt[0];
#pragma unroll
            for (int wq = 1; wq < 4; ++wq)
                if (better(s.mrgv[wq], s.mrgi[wq], bv, bi_)) { bv = s.mrgv[wq]; bi_ = s.mrgi[wq]; bt = s.mrgt[wq]; }
            if (r == ridx) sel = bi_;
            __syncthreads();
            if (tid == bt) {
                lv[0]=lv[1]; li[0]=li[1]; lv[1]=lv[2]; li[1]=li[2];
                lv[2]=lv[3]; li[2]=li[3]; lv[3]=lv[4]; li[3]=li[4];
                lv[4] = -INFINITY; li[4] = 0x7fffffff;
            }
        }
    }
    for (int i = tid; i < DIM; i += NTHR) {
        const float e = E[(size_t)sel * DIM + i];
        s.sx[i] = e > 0.f ? e : ALPHA * e;
    }
    __syncthreads();
    if (tid < 192) {
        const int o = tid & 63, part = tid >> 6;
        const int c = jj + o + part * HDIM;
        float a = b_i[c];
        a = dot256(Wx, s.sx, c, 0, a);
        a = dot256(Wx, s.sx + KH, c, KH, a);
        s.dd[part][o] = a;
    }
    __syncthreads();
    if (tid < 64) {
        const int c = jj + tid;
        const float xz = s.dd[0][tid], xr = s.dd[1][tid], xh = s.dd[2][tid];
        const float* hgb = hg + (size_t)bat * G3H;
        const float hz = hgb[c], hr = hgb[c + HDIM], hh = hgb[c + 2 * HDIM];
        const float z    = 1.f / (1.f + expf(-(xz + hz)));
        const float r    = 1.f / (1.f + expf(-(xr + hr)));
        const float cand = tanhf(xh + r * hh);
        const float hold = hcur[bat * HDIM + c];
        hnxt[bat * HDIM + c] = z * hold + (1.f - z) * cand;
    }
}

static __global__ void __launch_bounds__(NTHR, 1)
gru_coop(const float* __restrict__ E,  const float* __restrict__ Wx,
         const float* __restrict__ U,  const float* __restrict__ b_i,
         const float* __restrict__ b_r,const float* __restrict__ Wo,
         const float* __restrict__ bo, const float* __restrict__ ctx,
         const int* __restrict__ rix,  float* __restrict__ out,
         float* __restrict__ hbuf,     float* __restrict__ hg,
         float* __restrict__ pval,     int* __restrict__ pidx)
{
    cg::grid_group grid = cg::this_grid();
    const int j = blockIdx.x, tid = threadIdx.x;
    __shared__ SMem s;
    {
        const int g1 = j * NTHR + tid;
        if (g1 < (BATCH * HDIM) / 4) ((float4*)hbuf)[g1] = ((const float4*)ctx)[g1];
    }
    prologue_hg(s, j, tid, U, b_r, ctx, hg);
    grid.sync();
    for (int t = 0; t < TSTEPS; ++t) {
        const int p = t & 1;
        const float* hcur = hbuf + p * (BATCH * HDIM);
        float*       hnxt = hbuf + (p ^ 1) * (BATCH * HDIM);
        phaseB(s, j, tid, t, E, Wx, b_i, rix, hg, pval, pidx, hcur, hnxt);
        grid.sync();
        phaseA(s, j, tid, t, U, b_r, Wo, bo, hnxt, out, hg, pval, pidx);
        grid.sync();
    }
}

static __global__ void __launch_bounds__(NTHR, 1)
k_prologue(const float* __restrict__ U, const float* __restrict__ b_r,
           const float* __restrict__ ctx, float* __restrict__ hbuf,
           float* __restrict__ hg)
{
    __shared__ SMem s;
    const int j = blockIdx.x, tid = threadIdx.x;
    const int g1 = j * NTHR + tid;
    if (g1 < (BATCH * HDIM) / 4) ((float4*)hbuf)[g1] = ((const float4*)ctx)[g1];
    prologue_hg(s, j, tid, U, b_r, ctx, hg);
}

static __global__ void __launch_bounds__(NTHR, 1)
k_phaseB(int t, const float* __restrict__ E, const float* __restrict__ Wx,
         const float* __restrict__ b_i, const int* __restrict__ rix,
         const float* __restrict__ hg, const float* __restrict__ pval,
         const int* __restrict__ pidx, float* __restrict__ hbuf)
{
    __shared__ SMem s;
    const int p = t & 1;
    phaseB(s, blockIdx.x, threadIdx.x, t, E, Wx, b_i, rix, hg, pval, pidx,
           hbuf + p * (BATCH * HDIM), hbuf + (p ^ 1) * (BATCH * HDIM));
}

static __global__ void __launch_bounds__(NTHR, 1)
k_phaseA(int t, const float* __restrict__ U, const float* __restrict__ b_r,
         const float* __restrict__ Wo, const float* __restrict__ bo,
         const float* __restrict__ hbuf, float* __restrict__ out,
         float* __restrict__ hg, float* __restrict__ pval, int* __restrict__ pidx)
{
    __shared__ SMem s;
    const int p = t & 1;
    phaseA(s, blockIdx.x, threadIdx.x, t, U, b_r, Wo, bo,
           hbuf + (p ^ 1) * (BATCH * HDIM), out, hg, pval, pidx);
}

// =====================================================================
extern "C" void kernel_launch(void* const* d_in, const int* in_sizes, int n_in,
                              void* d_out, int out_size, void* d_ws, size_t ws_size,
                              hipStream_t stream) {
    (void)in_sizes; (void)n_in; (void)out_size;
    const float* E   = (const float*)d_in[0];
    const float* Wx  = (const float*)d_in[1];
    const float* U   = (const float*)d_in[2];
    const float* b_i = (const float*)d_in[3];
    const float* b_r = (const float*)d_in[4];
    const float* Wo  = (const float*)d_in[5];
    const float* bo  = (const float*)d_in[6];
    const float* ctx = (const float*)d_in[7];
    const int*   rix = (const int*)d_in[8];
    float* out = (float*)d_out;

    int dev = 0;
    (void)hipGetDevice(&dev);
    int coopAttr = 0, numCU = 0;
    (void)hipDeviceGetAttribute(&coopAttr, hipDeviceAttributeCooperativeLaunch, dev);
    (void)hipDeviceGetAttribute(&numCU, hipDeviceAttributeMultiprocessorCount, dev);

    // ---- new MFMA path ws layout (bytes) ----
    const size_t oWoPk = 0;            // 512*32000*2      = 32,768,000
    const size_t oWoT  = 32768000;     // 32000*512*4      = 65,536,000
    const size_t oUT   = 98304000;     // 1536*512*4       =  3,145,728
    const size_t oWxT  = 101449728;    // 1536*512*4       =  3,145,728
    const size_t oh2   = 104595456;    // 32*512*4         =     65,536
    const size_t ohg   = 104660992;    // 32*1536*4        =    196,608
    const size_t opval = 104857600;    // 32*256*5*4       =    163,840
    const size_t opidx = 105021440;    //                  =    163,840
    const size_t oexV  = 105185280;    // 32*8*4           =      1,024
    const size_t oexI  = 105186304;    //                  =      1,024
    const size_t need  = 105187328;

    bool launched = false;
    if (coopAttr && ws_size >= need) {
        int maxBlk = 0;
        (void)hipOccupancyMaxActiveBlocksPerMultiprocessor(&maxBlk, gru_mfma, NTHR, 0);
        if (maxBlk >= 1 && (long)maxBlk * numCU >= NBLK) {
            char* w = (char*)d_ws;
            unsigned* WoPk = (unsigned*)(w + oWoPk);
            float* WoT  = (float*)(w + oWoT);
            float* UT   = (float*)(w + oUT);
            float* WxT  = (float*)(w + oWxT);
            float* h2   = (float*)(w + oh2);
            float* hg   = (float*)(w + ohg);
            float* pval = (float*)(w + opval);
            int*   pidx = (int*)(w + opidx);
            float* exV  = (float*)(w + oexV);
            int*   exI  = (int*)(w + oexI);
            void* args[] = {&E, &Wx, &U, &b_i, &b_r, &Wo, &bo, &ctx, &rix, &out,
                            &WoPk, &WoT, &UT, &WxT, &h2, &hg, &pval, &pidx, &exV, &exI};
            if (hipLaunchCooperativeKernel(gru_mfma, dim3(NBLK), dim3(NTHR),
                                           args, 0u, stream) == hipSuccess) launched = true;
            else (void)hipGetLastError();
        }
    }

    if (!launched) {
        // ---- proven round-2 f32 path ----
        float* ws   = (float*)d_ws;
        float* hbuf = ws;
        float* hg   = ws + 32768;
        float* pval = ws + 81920;
        int*   pidx = (int*)(ws + 122880);
        bool coop_done = false;
        if (coopAttr) {
            int maxBlk = 0;
            (void)hipOccupancyMaxActiveBlocksPerMultiprocessor(&maxBlk, gru_coop, NTHR, 0);
            if (maxBlk >= 1 && (long)maxBlk * numCU >= NBLK) {
                void* args[] = {&E, &Wx, &U, &b_i, &b_r, &Wo, &bo, &ctx, &rix,
                                &out, &hbuf, &hg, &pval, &pidx};
                if (hipLaunchCooperativeKernel(gru_coop, dim3(NBLK), dim3(NTHR),
                                               args, 0u, stream) == hipSuccess) coop_done = true;
                else (void)hipGetLastError();
            }
        }
        if (!coop_done) {
            k_prologue<<<dim3(NBLK), dim3(NTHR), 0, stream>>>(U, b_r, ctx, hbuf, hg);
            for (int t = 0; t < TSTEPS; ++t) {
                k_phaseB<<<dim3(NBLK), dim3(NTHR), 0, stream>>>(t, E, Wx, b_i, rix,
                                                                hg, pval, pidx, hbuf);
                k_phaseA<<<dim3(NBLK), dim3(NTHR), 0, stream>>>(t, U, b_r, Wo, bo,
                                                                hbuf, out, hg, pval, pidx);
            }
        }
    }
}